// Round 1
// baseline (849.537 us; speedup 1.0000x reference)
//
#include <hip/hip_runtime.h>

// Problem constants (from reference): B=2048, H=512, K=10, A=80, L=1024
constexpr int B_ = 2048;
constexpr int H_ = 512;
constexpr int K_ = 10;
constexpr int A_ = 80;
constexpr int L_ = 1024;
constexpr int IN_ = A_ + 3 + H_;   // 595
constexpr int NT = 320;            // 5 waves; 320 = 16 l-groups * 20 float4-cols

__device__ __forceinline__ float softplus_stable(float x) {
    // log(1+exp(x)) = max(x,0) + log1p(exp(-|x|))
    return fmaxf(x, 0.0f) + log1pf(__expf(-fabsf(x)));
}

__global__ __launch_bounds__(NT) void attn_fused_kernel(
    const float* __restrict__ hidden,       // (B,H)
    const float* __restrict__ prev_window,  // (B,A)
    const float* __restrict__ prev_kappa,   // (B,K)
    const float* __restrict__ inputs3,      // (B,3)
    const float* __restrict__ char_seq,     // (B,L,A)
    const float* __restrict__ W,            // (3K, IN)
    const float* __restrict__ bias,         // (3K)
    const int*   __restrict__ lengths,      // (B)
    float* __restrict__ out_context,        // (B,A)
    float* __restrict__ out_kappa,          // (B,K)
    float* __restrict__ out_phi)            // (B,L)
{
    const int b = blockIdx.x;
    const int t = threadIdx.x;

    __shared__ float s_attn[IN_];
    __shared__ float s_alpha[K_];
    __shared__ float s_c[K_];      // -0.5 / beta^2
    __shared__ float s_kap[K_];
    __shared__ float s_phi[L_];
    __shared__ float4 s_red[16][20];

    // ---------------- Phase 1: stage attn_in, 30 dot products, softplus ----
    for (int i = t; i < IN_; i += NT) {
        float v;
        if (i < A_)            v = prev_window[(size_t)b * A_ + i];
        else if (i < A_ + 3)   v = inputs3[(size_t)b * 3 + (i - A_)];
        else                   v = hidden[(size_t)b * H_ + (i - A_ - 3)];
        s_attn[i] = v;
    }
    __syncthreads();

    if (t < 240) {                         // 30 outputs x 8-lane groups
        const int j = t >> 3;              // output index 0..29
        const int g = t & 7;               // lane within group
        const float* wrow = W + (size_t)j * IN_;
        float partial = 0.0f;
        for (int i = g; i < IN_; i += 8)
            partial += s_attn[i] * wrow[i];
        // reduce across the 8 contiguous lanes of the group
        partial += __shfl_down(partial, 4, 8);
        partial += __shfl_down(partial, 2, 8);
        partial += __shfl_down(partial, 1, 8);
        if (g == 0) {
            float sp = softplus_stable(partial + bias[j]);
            if (j < K_) {
                s_alpha[j] = sp;
            } else if (j < 2 * K_) {
                float be = fmaxf(sp, 0.01f);
                s_c[j - K_] = -0.5f / (be * be);
            } else {
                int k = j - 2 * K_;
                float kap = prev_kappa[(size_t)b * K_ + k] + sp * (1.0f / 25.0f);
                s_kap[k] = kap;
                out_kappa[(size_t)b * K_ + k] = kap;
            }
        }
    }
    __syncthreads();

    // ---------------- Phase 2: phi row (masked) ----------------------------
    const int len = lengths[b];
    for (int l = t; l < L_; l += NT) {
        float ph = 0.0f;
        if (l < len) {
            const float lf = (float)l;
            #pragma unroll
            for (int k = 0; k < K_; ++k) {
                float d = s_kap[k] - lf;
                ph += s_alpha[k] * __expf(s_c[k] * d * d);
            }
        }
        s_phi[l] = ph;
        out_phi[(size_t)b * L_ + l] = ph;
    }
    __syncthreads();

    // ---------------- Phase 3: context = sum_l phi[l] * char_seq[l,:] ------
    const int a4 = t % 20;                 // float4 column within the 80-wide row
    const int lg = t / 20;                 // 0..15 l-group
    const float4* cs4 = (const float4*)char_seq + (size_t)b * (L_ * 20);

    float4 acc = make_float4(0.f, 0.f, 0.f, 0.f);
    for (int l = lg; l < len; l += 16) {
        const float p = s_phi[l];
        const float4 v = cs4[(size_t)l * 20 + a4];
        acc.x += p * v.x;
        acc.y += p * v.y;
        acc.z += p * v.z;
        acc.w += p * v.w;
    }
    s_red[lg][a4] = acc;
    __syncthreads();

    for (int s = 8; s > 0; s >>= 1) {
        if (lg < s) {
            float4 o = s_red[lg + s][a4];
            float4 m = s_red[lg][a4];
            m.x += o.x; m.y += o.y; m.z += o.z; m.w += o.w;
            s_red[lg][a4] = m;
        }
        __syncthreads();
    }

    if (t < 20) {
        ((float4*)out_context)[(size_t)b * 20 + t] = s_red[0][t];
    }
}

extern "C" void kernel_launch(void* const* d_in, const int* in_sizes, int n_in,
                              void* d_out, int out_size, void* d_ws, size_t ws_size,
                              hipStream_t stream) {
    const float* hidden      = (const float*)d_in[0];
    const float* prev_window = (const float*)d_in[1];
    const float* prev_kappa  = (const float*)d_in[2];
    const float* inputs3     = (const float*)d_in[3];
    const float* char_seq    = (const float*)d_in[4];
    const float* W           = (const float*)d_in[5];
    const float* bias        = (const float*)d_in[6];
    const int*   lengths     = (const int*)d_in[7];

    float* out       = (float*)d_out;
    float* out_ctx   = out;                                   // B*A
    float* out_kappa = out + (size_t)B_ * A_;                 // B*K
    float* out_phi   = out + (size_t)B_ * A_ + (size_t)B_ * K_; // B*L

    attn_fused_kernel<<<B_, NT, 0, stream>>>(
        hidden, prev_window, prev_kappa, inputs3, char_seq, W, bias, lengths,
        out_ctx, out_kappa, out_phi);
}

// Round 2
// 758.142 us; speedup vs baseline: 1.1206x; 1.1206x over previous
//
#include <hip/hip_runtime.h>

// Problem constants (from reference): B=2048, H=512, K=10, A=80, L=1024
constexpr int B_ = 2048;
constexpr int H_ = 512;
constexpr int K_ = 10;
constexpr int A_ = 80;
constexpr int L_ = 1024;
constexpr int IN_ = A_ + 3 + H_;   // 595
constexpr int NT = 320;            // 5 waves; 320 = 16 l-groups * 20 float4-cols

// phi contributions below EPS are dropped from the context sum and phi output.
// Worst-case context perturbation: L * K * EPS * |char| ~ 1e-4 << 0.765 threshold.
#define LN_EPS (-20.723f)   // ln(1e-9)

__device__ __forceinline__ float softplus_stable(float x) {
    // log(1+exp(x)) = max(x,0) + log1p(exp(-|x|))
    return fmaxf(x, 0.0f) + log1pf(__expf(-fabsf(x)));
}

__global__ __launch_bounds__(NT) void attn_fused_kernel(
    const float* __restrict__ hidden,       // (B,H)
    const float* __restrict__ prev_window,  // (B,A)
    const float* __restrict__ prev_kappa,   // (B,K)
    const float* __restrict__ inputs3,      // (B,3)
    const float* __restrict__ char_seq,     // (B,L,A)
    const float* __restrict__ W,            // (3K, IN)
    const float* __restrict__ bias,         // (3K)
    const int*   __restrict__ lengths,      // (B)
    float* __restrict__ out_context,        // (B,A)
    float* __restrict__ out_kappa,          // (B,K)
    float* __restrict__ out_phi)            // (B,L)
{
    const int b = blockIdx.x;
    const int t = threadIdx.x;

    __shared__ float s_attn[IN_];
    __shared__ float s_alpha[K_];
    __shared__ float s_c[K_];      // -0.5 / beta^2
    __shared__ float s_kap[K_];
    __shared__ float s_cand[K_];   // per-component support bound kappa_k + d_max,k
    __shared__ float s_phi[L_];
    __shared__ float4 s_red[16][20];

    // ---------------- Phase 1: stage attn_in, 30 dot products, softplus ----
    for (int i = t; i < IN_; i += NT) {
        float v;
        if (i < A_)            v = prev_window[(size_t)b * A_ + i];
        else if (i < A_ + 3)   v = inputs3[(size_t)b * 3 + (i - A_)];
        else                   v = hidden[(size_t)b * H_ + (i - A_ - 3)];
        s_attn[i] = v;
    }
    __syncthreads();

    if (t < 240) {                         // 30 outputs x 8-lane groups
        const int j = t >> 3;              // output index 0..29
        const int g = t & 7;               // lane within group
        const float* wrow = W + (size_t)j * IN_;
        float partial = 0.0f;
        for (int i = g; i < IN_; i += 8)
            partial += s_attn[i] * wrow[i];
        partial += __shfl_down(partial, 4, 8);
        partial += __shfl_down(partial, 2, 8);
        partial += __shfl_down(partial, 1, 8);
        if (g == 0) {
            float sp = softplus_stable(partial + bias[j]);
            if (j < K_) {
                s_alpha[j] = sp;
            } else if (j < 2 * K_) {
                float be = fmaxf(sp, 0.01f);
                s_c[j - K_] = -0.5f / (be * be);
            } else {
                int k = j - 2 * K_;
                float kap = prev_kappa[(size_t)b * K_ + k] + sp * (1.0f / 25.0f);
                s_kap[k] = kap;
                out_kappa[(size_t)b * K_ + k] = kap;
            }
        }
    }
    __syncthreads();

    // ---------------- Phase 1b: per-component support bound -----------------
    // component k falls below EPS beyond kappa_k + sqrt((ln(alpha_k)-LN_EPS)/(-c_k))
    if (t < K_) {
        float a = s_alpha[t];
        float lognum = __logf(fmaxf(a, 1e-30f)) - LN_EPS;   // ln(alpha/eps)
        float d2 = fmaxf(lognum, 0.0f) / (-s_c[t]);         // d_max^2
        s_cand[t] = s_kap[t] + __fsqrt_rn(d2);
    }
    __syncthreads();

    const int len = lengths[b];
    float bound = 0.0f;
    #pragma unroll
    for (int k = 0; k < K_; ++k) bound = fmaxf(bound, s_cand[k]);
    const int l_hi = min(len, (int)ceilf(bound) + 2);       // rows [0, l_hi) matter

    // ---------------- Phase 2: phi row (only [0, l_hi) is nonzero) ----------
    for (int l = t; l < L_; l += NT) {
        float ph = 0.0f;
        if (l < l_hi) {
            const float lf = (float)l;
            #pragma unroll
            for (int k = 0; k < K_; ++k) {
                float d = s_kap[k] - lf;
                ph += s_alpha[k] * __expf(s_c[k] * d * d);
            }
        }
        if (l < l_hi) s_phi[l] = ph;
        out_phi[(size_t)b * L_ + l] = ph;
    }
    __syncthreads();

    // ---------------- Phase 3: context = sum_{l<l_hi} phi[l] * char_seq[l,:] -
    const int a4 = t % 20;                 // float4 column within the 80-wide row
    const int lg = t / 20;                 // 0..15 l-group
    const float4* cs4 = (const float4*)char_seq + (size_t)b * (L_ * 20);

    float4 acc = make_float4(0.f, 0.f, 0.f, 0.f);
    for (int l = lg; l < l_hi; l += 16) {
        const float p = s_phi[l];
        const float4 v = cs4[(size_t)l * 20 + a4];
        acc.x += p * v.x;
        acc.y += p * v.y;
        acc.z += p * v.z;
        acc.w += p * v.w;
    }
    s_red[lg][a4] = acc;
    __syncthreads();

    for (int s = 8; s > 0; s >>= 1) {
        if (lg < s) {
            float4 o = s_red[lg + s][a4];
            float4 m = s_red[lg][a4];
            m.x += o.x; m.y += o.y; m.z += o.z; m.w += o.w;
            s_red[lg][a4] = m;
        }
        __syncthreads();
    }

    if (t < 20) {
        ((float4*)out_context)[(size_t)b * 20 + t] = s_red[0][t];
    }
}

extern "C" void kernel_launch(void* const* d_in, const int* in_sizes, int n_in,
                              void* d_out, int out_size, void* d_ws, size_t ws_size,
                              hipStream_t stream) {
    const float* hidden      = (const float*)d_in[0];
    const float* prev_window = (const float*)d_in[1];
    const float* prev_kappa  = (const float*)d_in[2];
    const float* inputs3     = (const float*)d_in[3];
    const float* char_seq    = (const float*)d_in[4];
    const float* W           = (const float*)d_in[5];
    const float* bias        = (const float*)d_in[6];
    const int*   lengths     = (const int*)d_in[7];

    float* out       = (float*)d_out;
    float* out_ctx   = out;                                     // B*A
    float* out_kappa = out + (size_t)B_ * A_;                   // B*K
    float* out_phi   = out + (size_t)B_ * A_ + (size_t)B_ * K_; // B*L

    attn_fused_kernel<<<B_, NT, 0, stream>>>(
        hidden, prev_window, prev_kappa, inputs3, char_seq, W, bias, lengths,
        out_ctx, out_kappa, out_phi);
}